// Round 4
// baseline (99467.017 us; speedup 1.0000x reference)
//
#include <hip/hip_runtime.h>

// ---------------------------------------------------------------------------
// Bayesian LSTM forward: B=256, L=512, K=128, H=512 (4H = 2048)
//
// 256 persistent blocks (1/CU, cooperative launch).
//   group grp (0..15) = 16 batch rows; slice s (0..15) = 32 hidden units.
// Per step: GEMM [16 x 640] x [640 x 128], weights stationary in VGPRs.
//
// Cross-block h exchange (gfx9 scope bits: 00=CU, sc0=XCC, sc1=device):
//  - L2 fast path (runtime XCC_ID discovery proves 32 blocks/XCD): groups are
//    XCD-local; comm via sc0 stores/loads (XCC scope, coherent in the XCD L2).
//  - Safety nets: per-wave watchdog poll -> sticky device-scope fallback; and
//    producers mirror h+flag at agent scope (same addresses, same values =
//    idempotent) until a confirm counter proves the fast path works globally.
//  - Placement anomaly: pure round-2 device-scope protocol.
// Flags: per-producer slots, step-tag values, ring of 4 (no reset, no RMW).
// ---------------------------------------------------------------------------

typedef __attribute__((ext_vector_type(8))) __bf16 bf16x8;
typedef __attribute__((ext_vector_type(4))) float f32x4;
typedef __attribute__((ext_vector_type(8))) unsigned short us8;
typedef __attribute__((ext_vector_type(4))) unsigned int u32x4;

union U8 { us8 v; unsigned short u[8]; };

#define WFRAG_OFF   0u           // 1310720 ushort = 2621440 B
#define HBUF_OFF    2621440u     // 2*256*512 ushort = 524288 B
#define FLAGS_OFF   3145728u     // 1024 flags + 8 xcnt + bar + confirm
#define PART_OFF    3178496u     // 512 float
#define WS_NEEDED   3180544u

#define LOSS_OFF    67108864u
#define HT_OFF      67108865u
#define CT_OFF      67239937u

#define WDOG_LIM    (1u << 20)

__device__ __forceinline__ unsigned short f2bf(float f) {
  unsigned int u = __builtin_bit_cast(unsigned int, f);
  unsigned int r = (u + 0x7FFFu + ((u >> 16) & 1u)) >> 16;
  return (unsigned short)r;
}
__device__ __forceinline__ float sigm(float v) {
  return __builtin_amdgcn_rcpf(1.0f + __expf(-v));
}
__device__ __forceinline__ float tanh_f(float v) {
  return 1.0f - 2.0f * __builtin_amdgcn_rcpf(__expf(2.0f * v) + 1.0f);
}

#define BAR_LGKM() asm volatile("s_waitcnt lgkmcnt(0)\n\ts_barrier" ::: "memory")
#define BAR_VM()   asm volatile("s_waitcnt vmcnt(0)\n\ts_barrier" ::: "memory")

// 4x16B batched loads; F = cache scope flags
#define LDX4(d0,d1,d2,d3,p0,p1,p2,p3,F)                                  \
  asm volatile("global_load_dwordx4 %0, %4, off " F "\n\t"               \
               "global_load_dwordx4 %1, %5, off " F "\n\t"               \
               "global_load_dwordx4 %2, %6, off " F "\n\t"               \
               "global_load_dwordx4 %3, %7, off " F "\n\t"               \
               "s_waitcnt vmcnt(0)"                                      \
               : "=&v"(d0), "=&v"(d1), "=&v"(d2), "=&v"(d3)              \
               : "v"(p0), "v"(p1), "v"(p2), "v"(p3) : "memory")

__device__ __forceinline__ int ld_flag_fast(const int* p) {   // XCC scope
  int v;
  asm volatile("global_load_dword %0, %1, off sc0\n\t"
               "s_waitcnt vmcnt(0)" : "=v"(v) : "v"(p) : "memory");
  return v;
}
__device__ __forceinline__ int ld_flag_slow(const int* p) {   // system scope
  int v;
  asm volatile("global_load_dword %0, %1, off sc0 sc1\n\t"
               "s_waitcnt vmcnt(0)" : "=v"(v) : "v"(p) : "memory");
  return v;
}
__device__ __forceinline__ void st_fast(unsigned int* p, unsigned int v) {
  asm volatile("global_store_dword %0, %1, off sc0" :: "v"(p), "v"(v) : "memory");
}

// ---------------- prep: weight fragments (bf16, MFMA B layout) + zero sync --
__global__ void prep_w(const float* __restrict__ whh, const float* __restrict__ wih,
                       unsigned short* __restrict__ w_frag, int* __restrict__ flags) {
  int gid = blockIdx.x * 256 + threadIdx.x;
  if (gid < 1040) flags[gid] = 0;   // flags[1024] + xcnt[8] + bar + confirm
  if (gid >= 163840) return;
  int lane = gid & 63;
  int t3 = gid >> 6;
  int fr = t3 % 40;
  int w  = (t3 / 40) & 3;
  int s  = t3 / 160;
  int kt = fr % 20, ct = fr / 20;
  int gc = (w << 9) + (s << 5) + (ct << 4) + (lane & 15);
  int kbase = (kt << 5) + ((lane >> 4) << 3);
  U8 p;
#pragma unroll
  for (int j = 0; j < 8; ++j) {
    int k = kbase + j;
    float v = (k < 512) ? whh[k * 2048 + gc] : wih[(k - 512) * 2048 + gc];
    p.u[j] = f2bf(v);
  }
  *(us8*)&w_frag[(size_t)gid * 8] = p.v;
}

// ---------------- bayes loss: block partials ---------------------------------
__global__ void loss_k(const float* __restrict__ whh, const float* __restrict__ wih,
                       const float* __restrict__ bias,
                       const float* __restrict__ whh_mu, const float* __restrict__ whh_rho,
                       const float* __restrict__ wih_mu, const float* __restrict__ wih_rho,
                       const float* __restrict__ b_mu, const float* __restrict__ b_rho,
                       float* __restrict__ partials) {
  int gid = blockIdx.x * 256 + threadIdx.x;
  float acc = 0.f;
  for (int idx = gid; idx < 1312768; idx += 131072) {
    float p, mu, rho;
    if (idx < 1048576)      { p = whh[idx];           mu = whh_mu[idx];           rho = whh_rho[idx]; }
    else if (idx < 1310720) { int i = idx - 1048576;  p = wih[i]; mu = wih_mu[i]; rho = wih_rho[i]; }
    else                    { int i = idx - 1310720;  p = bias[i]; mu = b_mu[i];  rho = b_rho[i]; }
    float sig = log1pf(__expf(rho));
    float d = p - mu;
    float vari = -0.57236494f - logf(sig) - d * d / (2.f * sig * sig);
    float lp1 = -0.91893853f - 0.5f * p * p;
    float lp2 = 5.98881675f - 500000.f * p * p;
    float prior = logf(0.5f * (__expf(lp1) + __expf(lp2)));
    acc += vari - prior;
  }
#pragma unroll
  for (int off = 32; off; off >>= 1) acc += __shfl_down(acc, off, 64);
  __shared__ float wsum[4];
  if ((threadIdx.x & 63) == 0) wsum[threadIdx.x >> 6] = acc;
  __syncthreads();
  if (threadIdx.x == 0) partials[blockIdx.x] = wsum[0] + wsum[1] + wsum[2] + wsum[3];
}

// ---------------- persistent LSTM kernel -------------------------------------
__launch_bounds__(256, 1)
__global__ void lstm_k(const float* __restrict__ x,
                       const unsigned short* __restrict__ w_frag,
                       const float* __restrict__ bias,
                       unsigned short* __restrict__ h_buf,
                       int* __restrict__ flags,
                       const float* __restrict__ partials,
                       float* __restrict__ out) {
  __shared__ unsigned short A_sh[16][648];     // [row][k] h(0..511)|x(512..639)
  __shared__ float gates_sh[2][16][132];       // double-buffered epilogue
  __shared__ int sh_i[2];
  __shared__ int sh_trip;                      // any wave tripped the watchdog
  __shared__ int sh_done;                      // grid confirmed: stop mirroring

  const int tid  = threadIdx.x;
  const int lane = tid & 63;
  const int wv   = tid >> 6;                   // gate chunk (i,f,g,o)
  const int bid  = blockIdx.x;
  int* xcnt    = flags + 1024;
  int* bar     = flags + 1032;
  int* confirm = flags + 1033;

  // ---- placement discovery + grid barrier ---------------------------------
  unsigned int xreg;
  asm volatile("s_getreg_b32 %0, hwreg(HW_REG_XCC_ID)" : "=s"(xreg));
  const int my_xcd = (int)(xreg & 7u);
  if (tid == 0) {
    sh_trip = 0; sh_done = 0;
    sh_i[0] = atomicAdd(&xcnt[my_xcd], 1);
  }
  __syncthreads();
  const int rank = sh_i[0];
  if (tid == 0) {
    __hip_atomic_fetch_add(bar, 1, __ATOMIC_RELAXED, __HIP_MEMORY_SCOPE_AGENT);
    while (__hip_atomic_load(bar, __ATOMIC_RELAXED, __HIP_MEMORY_SCOPE_AGENT) < 256)
      __builtin_amdgcn_s_sleep(1);
    int ok = 1;
    for (int i = 0; i < 8; ++i)
      ok &= (__hip_atomic_load(&xcnt[i], __ATOMIC_RELAXED, __HIP_MEMORY_SCOPE_AGENT) == 32);
    sh_i[1] = ok;
  }
  __syncthreads();
  const bool l2m = sh_i[1] != 0;
  int grp, s;
  if (l2m) { grp = (my_xcd << 1) | (rank >> 4); s = rank & 15; }   // XCD-local
  else     { grp = ((bid & 7) << 1) | ((bid >> 3) & 1); s = bid >> 4; }
  const int b0 = grp << 4;

  // ---- stationary B fragments: 40 x bf16x8 --------------------------------
  us8 bfr[40];
  {
    const us8* wfp = (const us8*)(w_frag + (size_t)s * 81920);
#pragma unroll
    for (int fr = 0; fr < 40; ++fr)
      bfr[fr] = wfp[(wv * 40 + fr) * 64 + lane];
  }

  // ---- bias folded into accumulator init (C col = lane&15) ----------------
  const float bv0 = bias[(wv << 9) + (s << 5) + (lane & 15)];
  const float bv1 = bias[(wv << 9) + (s << 5) + 16 + (lane & 15)];

  // ---- epilogue mapping ----------------------------------------------------
  const int r  = tid >> 4;
  const int uo = (tid & 15) << 1;
  const int ug = (s << 5) + uo;
  float c0 = 0.f, c1 = 0.f;

  const unsigned short* arow = &A_sh[lane & 15][(lane >> 4) << 3];

  // ---- x prefetch (1 step ahead, register-resident) ------------------------
  const int xrow = tid >> 4;
  const int f8 = (tid & 15) << 3;
  const float* xbase = x + (((size_t)(b0 + xrow) << 9) << 7) + f8;
  float4 xpA = *(const float4*)xbase;
  float4 xpB = *(const float4*)(xbase + 4);

  bool slow_wave = false;

  for (int t = 0; t < 512; ++t) {
    // ---- convert prefetched x_t -> LDS; issue prefetch for t+1 ------------
    {
      U8 p;
      p.u[0] = f2bf(xpA.x); p.u[1] = f2bf(xpA.y); p.u[2] = f2bf(xpA.z); p.u[3] = f2bf(xpA.w);
      p.u[4] = f2bf(xpB.x); p.u[5] = f2bf(xpB.y); p.u[6] = f2bf(xpB.z); p.u[7] = f2bf(xpB.w);
      *(us8*)&A_sh[xrow][512 + f8] = p.v;
      if (t < 511) {
        const float* xp = xbase + (size_t)(t + 1) * 128;
        xpA = *(const float4*)xp;
        xpB = *(const float4*)(xp + 4);
      }
    }
    BAR_LGKM();                                        // B1
    const bool mirror_on = l2m && (sh_done == 0);

    // ---- x-part MFMAs (off critical path, before the poll) ----------------
    f32x4 a0a = {bv0, bv0, bv0, bv0}, a0b = {0.f, 0.f, 0.f, 0.f};
    f32x4 a1a = {bv1, bv1, bv1, bv1}, a1b = {0.f, 0.f, 0.f, 0.f};
    {
      us8 xa0 = *(const us8*)(arow + (16 << 5));
      us8 xa1 = *(const us8*)(arow + (17 << 5));
      us8 xa2 = *(const us8*)(arow + (18 << 5));
      us8 xa3 = *(const us8*)(arow + (19 << 5));
      a0a = __builtin_amdgcn_mfma_f32_16x16x32_bf16(__builtin_bit_cast(bf16x8, xa0), __builtin_bit_cast(bf16x8, bfr[16]), a0a, 0, 0, 0);
      a1a = __builtin_amdgcn_mfma_f32_16x16x32_bf16(__builtin_bit_cast(bf16x8, xa0), __builtin_bit_cast(bf16x8, bfr[36]), a1a, 0, 0, 0);
      a0b = __builtin_amdgcn_mfma_f32_16x16x32_bf16(__builtin_bit_cast(bf16x8, xa1), __builtin_bit_cast(bf16x8, bfr[17]), a0b, 0, 0, 0);
      a1b = __builtin_amdgcn_mfma_f32_16x16x32_bf16(__builtin_bit_cast(bf16x8, xa1), __builtin_bit_cast(bf16x8, bfr[37]), a1b, 0, 0, 0);
      a0a = __builtin_amdgcn_mfma_f32_16x16x32_bf16(__builtin_bit_cast(bf16x8, xa2), __builtin_bit_cast(bf16x8, bfr[18]), a0a, 0, 0, 0);
      a1a = __builtin_amdgcn_mfma_f32_16x16x32_bf16(__builtin_bit_cast(bf16x8, xa2), __builtin_bit_cast(bf16x8, bfr[38]), a1a, 0, 0, 0);
      a0b = __builtin_amdgcn_mfma_f32_16x16x32_bf16(__builtin_bit_cast(bf16x8, xa3), __builtin_bit_cast(bf16x8, bfr[19]), a0b, 0, 0, 0);
      a1b = __builtin_amdgcn_mfma_f32_16x16x32_bf16(__builtin_bit_cast(bf16x8, xa3), __builtin_bit_cast(bf16x8, bfr[39]), a1b, 0, 0, 0);
    }

    if (t > 0) {
      // ---- poll the 16 producer tags ------------------------------------
      const int* fl = flags + (((t - 1) & 3) << 8) + (grp << 4) + (lane & 15);
      if (l2m && !slow_wave) {
        unsigned int iters = 0;
        bool trip = false;
        while (true) {
          int f = ld_flag_fast(fl);
          if (__all(f == t)) break;
          if (++iters > WDOG_LIM) { trip = true; break; }
        }
        if (trip) { sh_trip = 1; slow_wave = true; }
      }
      if (!l2m || slow_wave) {
        while (true) {
          int f = ld_flag_slow(fl);
          if (__all(f == t)) break;
          __builtin_amdgcn_s_sleep(1);
        }
      }
      // ---- gather h_t: 4x16B per thread -> LDS --------------------------
      const u32x4* hb = (const u32x4*)(h_buf + ((size_t)(t & 1) << 17)) + ((size_t)b0 << 6);
      u32x4 h0_, h1_, h2_, h3_;
      if (l2m && !slow_wave) {
        LDX4(h0_, h1_, h2_, h3_, hb + tid, hb + 256 + tid, hb + 512 + tid, hb + 768 + tid, "sc0");
      } else {
        LDX4(h0_, h1_, h2_, h3_, hb + tid, hb + 256 + tid, hb + 512 + tid, hb + 768 + tid, "sc0 sc1");
      }
      *(u32x4*)&A_sh[tid >> 6][(tid & 63) << 3]        = h0_;
      *(u32x4*)&A_sh[4 + (tid >> 6)][(tid & 63) << 3]  = h1_;
      *(u32x4*)&A_sh[8 + (tid >> 6)][(tid & 63) << 3]  = h2_;
      *(u32x4*)&A_sh[12 + (tid >> 6)][(tid & 63) << 3] = h3_;
      BAR_LGKM();                                      // B2

      // ---- h-part GEMM: 16 k-tiles x 2 cols, 4-way acc split --------------
      us8 areg[16];
#pragma unroll
      for (int kt = 0; kt < 16; ++kt)
        areg[kt] = *(const us8*)(arow + (kt << 5));
#pragma unroll
      for (int kt = 0; kt < 16; kt += 2) {
        a0a = __builtin_amdgcn_mfma_f32_16x16x32_bf16(__builtin_bit_cast(bf16x8, areg[kt]), __builtin_bit_cast(bf16x8, bfr[kt]), a0a, 0, 0, 0);
        a1a = __builtin_amdgcn_mfma_f32_16x16x32_bf16(__builtin_bit_cast(bf16x8, areg[kt]), __builtin_bit_cast(bf16x8, bfr[20 + kt]), a1a, 0, 0, 0);
        a0b = __builtin_amdgcn_mfma_f32_16x16x32_bf16(__builtin_bit_cast(bf16x8, areg[kt + 1]), __builtin_bit_cast(bf16x8, bfr[kt + 1]), a0b, 0, 0, 0);
        a1b = __builtin_amdgcn_mfma_f32_16x16x32_bf16(__builtin_bit_cast(bf16x8, areg[kt + 1]), __builtin_bit_cast(bf16x8, bfr[21 + kt]), a1b, 0, 0, 0);
      }
    }

    // ---- combine + scatter gates to LDS ------------------------------------
    {
      f32x4 acc0 = a0a + a0b;
      f32x4 acc1 = a1a + a1b;
      const int crow = (lane >> 4) << 2;
      const int ccol = lane & 15;
#pragma unroll
      for (int q = 0; q < 4; ++q) {
        gates_sh[t & 1][crow + q][(wv << 5) + ccol]      = acc0[q];
        gates_sh[t & 1][crow + q][(wv << 5) + 16 + ccol] = acc1[q];
      }
    }
    BAR_LGKM();                                        // B3

    // ---- gate math for 2 units of one row (bias already in acc) -----------
    float2 vi = *(const float2*)&gates_sh[t & 1][r][uo];
    float2 vf = *(const float2*)&gates_sh[t & 1][r][32 + uo];
    float2 vg = *(const float2*)&gates_sh[t & 1][r][64 + uo];
    float2 vo = *(const float2*)&gates_sh[t & 1][r][96 + uo];
    float it0 = sigm(vi.x), ft0 = sigm(vf.x), ot0 = sigm(vo.x);
    c0 = ft0 * c0 + it0 * tanh_f(vg.x);
    float h0 = ot0 * tanh_f(c0);
    float it1 = sigm(vi.y), ft1 = sigm(vf.y), ot1 = sigm(vo.y);
    c1 = ft1 * c1 + it1 * tanh_f(vg.y);
    float h1 = ot1 * tanh_f(c1);

    // ---- publish h_{t+1}: store -> drain -> barrier -> tag -----------------
    const size_t gb = (size_t)(b0 + r);
    unsigned int pk = (unsigned int)f2bf(h0) | ((unsigned int)f2bf(h1) << 16);
    unsigned int* hp = (unsigned int*)&h_buf[((size_t)((t + 1) & 1) << 17) + (gb << 9) + ug];
    int* fp = flags + ((t & 3) << 8) + (grp << 4) + s;
    if (l2m) st_fast(hp, pk);
    else     __hip_atomic_store(hp, pk, __ATOMIC_RELAXED, __HIP_MEMORY_SCOPE_AGENT);
    BAR_VM();                                          // B4
    if (tid == 0) {
      if (l2m) st_fast((unsigned int*)fp, (unsigned int)(t + 1));
      else     __hip_atomic_store(fp, t + 1, __ATOMIC_RELAXED, __HIP_MEMORY_SCOPE_AGENT);
    }
    if (mirror_on) {   // agent-scope mirror: same addresses, same values
      __hip_atomic_store(hp, pk, __ATOMIC_RELAXED, __HIP_MEMORY_SCOPE_AGENT);
      BAR_VM();                                        // B5
      if (tid == 0)
        __hip_atomic_store(fp, t + 1, __ATOMIC_RELAXED, __HIP_MEMORY_SCOPE_AGENT);
    }

    // ---- confirm / stop-mirroring bookkeeping (off critical path) ---------
    if (l2m && tid == 0) {
      if (t == 8 && sh_trip == 0)
        __hip_atomic_fetch_add(confirm, 1, __ATOMIC_RELAXED, __HIP_MEMORY_SCOPE_AGENT);
      if (t == 16 || t == 32 || t == 64 || t == 128 || t == 256) {
        if (__hip_atomic_load(confirm, __ATOMIC_RELAXED, __HIP_MEMORY_SCOPE_AGENT) == 256)
          sh_done = 1;
      }
    }

    // ---- off-critical-path output writes ----------------------------------
    float2 hv; hv.x = h0; hv.y = h1;
    *(float2*)&out[(((gb << 9) + t) << 9) + ug] = hv;
    if (t == 511) {
      float2 cv; cv.x = c0; cv.y = c1;
      *(float2*)&out[HT_OFF + (gb << 9) + ug] = hv;
      *(float2*)&out[CT_OFF + (gb << 9) + ug] = cv;
    }
  }

  // ---- block 0: finalize deterministic loss sum ---------------------------
  if (bid == 0) {
    float v = partials[tid] + partials[tid + 256];
#pragma unroll
    for (int off = 32; off; off >>= 1) v += __shfl_down(v, off, 64);
    __shared__ float lw[4];
    if ((tid & 63) == 0) lw[tid >> 6] = v;
    __syncthreads();
    if (tid == 0) out[LOSS_OFF] = lw[0] + lw[1] + lw[2] + lw[3];
  }
}

// ---------------------------------------------------------------------------
extern "C" void kernel_launch(void* const* d_in, const int* in_sizes, int n_in,
                              void* d_out, int out_size, void* d_ws, size_t ws_size,
                              hipStream_t stream) {
  if (ws_size < WS_NEEDED) return;
  const float* x       = (const float*)d_in[0];
  const float* whh     = (const float*)d_in[1];
  const float* wih     = (const float*)d_in[2];
  const float* bias    = (const float*)d_in[3];
  const float* whh_mu  = (const float*)d_in[4];
  const float* whh_rho = (const float*)d_in[5];
  const float* wih_mu  = (const float*)d_in[6];
  const float* wih_rho = (const float*)d_in[7];
  const float* b_mu    = (const float*)d_in[8];
  const float* b_rho   = (const float*)d_in[9];
  char* ws = (char*)d_ws;
  unsigned short* w_frag = (unsigned short*)(ws + WFRAG_OFF);
  unsigned short* h_buf  = (unsigned short*)(ws + HBUF_OFF);
  int*            flags  = (int*)(ws + FLAGS_OFF);
  float*          parts  = (float*)(ws + PART_OFF);
  float*          out    = (float*)d_out;

  prep_w<<<640, 256, 0, stream>>>(whh, wih, w_frag, flags);
  loss_k<<<512, 256, 0, stream>>>(whh, wih, bias, whh_mu, whh_rho,
                                  wih_mu, wih_rho, b_mu, b_rho, parts);

  void* kargs[7];
  kargs[0] = (void*)&x;
  kargs[1] = (void*)&w_frag;
  kargs[2] = (void*)&bias;
  kargs[3] = (void*)&h_buf;
  kargs[4] = (void*)&flags;
  kargs[5] = (void*)&parts;
  kargs[6] = (void*)&out;
  hipLaunchCooperativeKernel((const void*)lstm_k, dim3(256), dim3(256),
                             kargs, 0, stream);
}

// Round 6
// 1359.417 us; speedup vs baseline: 73.1689x; 73.1689x over previous
//
#include <hip/hip_runtime.h>

// ---------------------------------------------------------------------------
// Bayesian LSTM forward: B=256, L=512, K=128, H=512 (4H = 2048)
//
// 256 persistent blocks (1/CU, cooperative launch).
//   group grp (0..15) = 16 batch rows; slice s (0..15) = 32 hidden units.
// Per step: GEMM [16 x 640] x [640 x 128], weights stationary in VGPRs.
//
// Cross-block h exchange: DATA-EMBEDDED-TAG protocol through L3 (sc1 = agent
// scope, the one proven-fast coherent path; round-4 showed sc0 scope games
// deadlock). Each 4B word = [tag:2 | q1:15 | q0:15], q = 15-bit fixed-point
// of h in (-1,1) (resolution 6.1e-5, better than bf16). Producer: ONE
// fire-and-forget sc1 store per thread -- no drain, no flag, no barrier.
// Consumer polls its 16 words until every tag == t&3. Ring of 2 buffers;
// distance-2 overwrite is flow-controlled by the all-to-all dependence
// (publish(t) requires all peers published t-1, which requires they consumed
// t-2 -- the data being overwritten). Ring is zero-initialized (tag 0) so
// 0xAA workspace poison can never validate.
// ---------------------------------------------------------------------------

typedef __attribute__((ext_vector_type(8))) __bf16 bf16x8;
typedef __attribute__((ext_vector_type(4))) float f32x4;
typedef __attribute__((ext_vector_type(8))) unsigned short us8;
typedef __attribute__((ext_vector_type(4))) unsigned int u32x4;

union U8 { us8 v; unsigned short u[8]; };
union O8 { us8 v; unsigned int w[4]; };

#define WFRAG_OFF   0u           // 1310720 ushort = 2621440 B
#define HBUF_OFF    2621440u     // 2 bufs * 65536 u32 words = 524288 B
#define PART_OFF    3178496u     // 512 float
#define WS_NEEDED   3180544u

#define LOSS_OFF    67108864u
#define HT_OFF      67108865u
#define CT_OFF      67239937u

__device__ __forceinline__ unsigned short f2bf(float f) {
  unsigned int u = __builtin_bit_cast(unsigned int, f);
  unsigned int r = (u + 0x7FFFu + ((u >> 16) & 1u)) >> 16;
  return (unsigned short)r;
}
__device__ __forceinline__ unsigned int pk_bf16(float a, float b) {
  unsigned int r;
  asm("v_cvt_pk_bf16_f32 %0, %1, %2" : "=v"(r) : "v"(a), "v"(b));
  return r;
}
__device__ __forceinline__ float sigm(float v) {
  return __builtin_amdgcn_rcpf(1.0f + __expf(-v));
}
__device__ __forceinline__ float tanh_f(float v) {
  return 1.0f - 2.0f * __builtin_amdgcn_rcpf(__expf(2.0f * v) + 1.0f);
}

#define BAR_LGKM() asm volatile("s_waitcnt lgkmcnt(0)\n\ts_barrier" ::: "memory")

// 64B tagged-h gather: 4x dwordx4 from one base pointer (agent scope).
// NOTE gfx950 asm modifier order: offset:N BEFORE sc1.
#define LDH(d0,d1,d2,d3,p)                                               \
  asm volatile("global_load_dwordx4 %0, %4, off sc1\n\t"                 \
               "global_load_dwordx4 %1, %4, off offset:16 sc1\n\t"       \
               "global_load_dwordx4 %2, %4, off offset:32 sc1\n\t"       \
               "global_load_dwordx4 %3, %4, off offset:48 sc1\n\t"       \
               "s_waitcnt vmcnt(0)"                                      \
               : "=&v"(d0), "=&v"(d1), "=&v"(d2), "=&v"(d3)              \
               : "v"(p) : "memory")

// ---------------- prep: weight fragments (bf16, MFMA B layout) + ring zero --
__global__ void prep_w(const float* __restrict__ whh, const float* __restrict__ wih,
                       unsigned short* __restrict__ w_frag,
                       unsigned int* __restrict__ h_words) {
  int gid = blockIdx.x * 256 + threadIdx.x;
  if (gid < 131072) h_words[gid] = 0;          // tag 0: poison can't validate
  if (gid >= 163840) return;
  int lane = gid & 63;
  int t3 = gid >> 6;
  int fr = t3 % 40;
  int w  = (t3 / 40) & 3;
  int s  = t3 / 160;
  int kt = fr % 20, ct = fr / 20;
  int gc = (w << 9) + (s << 5) + (ct << 4) + (lane & 15);
  int kbase = (kt << 5) + ((lane >> 4) << 3);
  U8 p;
#pragma unroll
  for (int j = 0; j < 8; ++j) {
    int k = kbase + j;
    float v = (k < 512) ? whh[k * 2048 + gc] : wih[(k - 512) * 2048 + gc];
    p.u[j] = f2bf(v);
  }
  *(us8*)&w_frag[(size_t)gid * 8] = p.v;
}

// ---------------- bayes loss: block partials ---------------------------------
__global__ void loss_k(const float* __restrict__ whh, const float* __restrict__ wih,
                       const float* __restrict__ bias,
                       const float* __restrict__ whh_mu, const float* __restrict__ whh_rho,
                       const float* __restrict__ wih_mu, const float* __restrict__ wih_rho,
                       const float* __restrict__ b_mu, const float* __restrict__ b_rho,
                       float* __restrict__ partials) {
  int gid = blockIdx.x * 256 + threadIdx.x;
  float acc = 0.f;
  for (int idx = gid; idx < 1312768; idx += 131072) {
    float p, mu, rho;
    if (idx < 1048576)      { p = whh[idx];           mu = whh_mu[idx];           rho = whh_rho[idx]; }
    else if (idx < 1310720) { int i = idx - 1048576;  p = wih[i]; mu = wih_mu[i]; rho = wih_rho[i]; }
    else                    { int i = idx - 1310720;  p = bias[i]; mu = b_mu[i];  rho = b_rho[i]; }
    float sig = log1pf(__expf(rho));
    float d = p - mu;
    float vari = -0.57236494f - logf(sig) - d * d / (2.f * sig * sig);
    float lp1 = -0.91893853f - 0.5f * p * p;
    float lp2 = 5.98881675f - 500000.f * p * p;
    float prior = logf(0.5f * (__expf(lp1) + __expf(lp2)));
    acc += vari - prior;
  }
#pragma unroll
  for (int off = 32; off; off >>= 1) acc += __shfl_down(acc, off, 64);
  __shared__ float wsum[4];
  if ((threadIdx.x & 63) == 0) wsum[threadIdx.x >> 6] = acc;
  __syncthreads();
  if (threadIdx.x == 0) partials[blockIdx.x] = wsum[0] + wsum[1] + wsum[2] + wsum[3];
}

// ---------------- persistent LSTM kernel -------------------------------------
__launch_bounds__(256, 1)
__global__ void lstm_k(const float* __restrict__ x,
                       const unsigned short* __restrict__ w_frag,
                       const float* __restrict__ bias,
                       unsigned int* __restrict__ h_words,
                       const float* __restrict__ partials,
                       float* __restrict__ out) {
  __shared__ unsigned short A_sh[16][648];     // [row][k] h(0..511)|x(512..639)
  __shared__ float gates_sh[2][16][132];       // double-buffered epilogue

  const int tid  = threadIdx.x;
  const int lane = tid & 63;
  const int wv   = tid >> 6;                   // gate chunk (i,f,g,o)
  const int bid  = blockIdx.x;
  const int grp = ((bid & 7) << 1) | ((bid >> 3) & 1);   // batch group 0..15
  const int s   = bid >> 4;                              // hidden slice 0..15
  const int b0 = grp << 4;

  // ---- stationary B fragments: 40 x bf16x8 --------------------------------
  us8 bfr[40];
  {
    const us8* wfp = (const us8*)(w_frag + (size_t)s * 81920);
#pragma unroll
    for (int fr = 0; fr < 40; ++fr)
      bfr[fr] = wfp[(wv * 40 + fr) * 64 + lane];
  }

  // ---- bias folded into accumulator init (C col = lane&15) ----------------
  const float bv0 = bias[(wv << 9) + (s << 5) + (lane & 15)];
  const float bv1 = bias[(wv << 9) + (s << 5) + 16 + (lane & 15)];

  // ---- epilogue mapping: thread -> (row r, units uo, uo+1) ----------------
  const int r  = tid >> 4;
  const int uo = (tid & 15) << 1;
  const int ug = (s << 5) + uo;
  float c0 = 0.f, c1 = 0.f;

  const unsigned short* arow = &A_sh[lane & 15][(lane >> 4) << 3];

  // ---- gather/publish word pointers (fixed per thread) --------------------
  // word(buf, grp, row, pair) = (buf<<16) | (grp<<12) | (row<<8) | pair
  const unsigned int gbase = (grp << 12) + ((tid >> 4) << 8) + ((tid & 15) << 4);
  const unsigned int pbase = (grp << 12) + (r << 8) + (s << 4) + (tid & 15);

  // ---- x prefetch (1 step ahead, register-resident) ------------------------
  const int xrow = tid >> 4;
  const int f8 = (tid & 15) << 3;
  const float* xbase = x + (((size_t)(b0 + xrow) << 9) << 7) + f8;
  float4 xpA = *(const float4*)xbase;
  float4 xpB = *(const float4*)(xbase + 4);

  const float DQ = 6.103701895199438e-05f;     // 1/16383.5

  for (int t = 0; t < 512; ++t) {
    // ---- convert prefetched x_t -> LDS; issue prefetch for t+1 ------------
    {
      U8 p;
      p.u[0] = f2bf(xpA.x); p.u[1] = f2bf(xpA.y); p.u[2] = f2bf(xpA.z); p.u[3] = f2bf(xpA.w);
      p.u[4] = f2bf(xpB.x); p.u[5] = f2bf(xpB.y); p.u[6] = f2bf(xpB.z); p.u[7] = f2bf(xpB.w);
      *(us8*)&A_sh[xrow][512 + f8] = p.v;
      if (t < 511) {
        const float* xp = xbase + (size_t)(t + 1) * 128;
        xpA = *(const float4*)xp;
        xpB = *(const float4*)(xp + 4);
      }
    }
    BAR_LGKM();                                        // B1

    // ---- x-part MFMAs (overlap producer stores landing in L3) -------------
    f32x4 a0a = {bv0, bv0, bv0, bv0}, a0b = {0.f, 0.f, 0.f, 0.f};
    f32x4 a1a = {bv1, bv1, bv1, bv1}, a1b = {0.f, 0.f, 0.f, 0.f};
    {
      us8 xa0 = *(const us8*)(arow + (16 << 5));
      us8 xa1 = *(const us8*)(arow + (17 << 5));
      us8 xa2 = *(const us8*)(arow + (18 << 5));
      us8 xa3 = *(const us8*)(arow + (19 << 5));
      a0a = __builtin_amdgcn_mfma_f32_16x16x32_bf16(__builtin_bit_cast(bf16x8, xa0), __builtin_bit_cast(bf16x8, bfr[16]), a0a, 0, 0, 0);
      a1a = __builtin_amdgcn_mfma_f32_16x16x32_bf16(__builtin_bit_cast(bf16x8, xa0), __builtin_bit_cast(bf16x8, bfr[36]), a1a, 0, 0, 0);
      a0b = __builtin_amdgcn_mfma_f32_16x16x32_bf16(__builtin_bit_cast(bf16x8, xa1), __builtin_bit_cast(bf16x8, bfr[17]), a0b, 0, 0, 0);
      a1b = __builtin_amdgcn_mfma_f32_16x16x32_bf16(__builtin_bit_cast(bf16x8, xa1), __builtin_bit_cast(bf16x8, bfr[37]), a1b, 0, 0, 0);
      a0a = __builtin_amdgcn_mfma_f32_16x16x32_bf16(__builtin_bit_cast(bf16x8, xa2), __builtin_bit_cast(bf16x8, bfr[18]), a0a, 0, 0, 0);
      a1a = __builtin_amdgcn_mfma_f32_16x16x32_bf16(__builtin_bit_cast(bf16x8, xa2), __builtin_bit_cast(bf16x8, bfr[38]), a1a, 0, 0, 0);
      a0b = __builtin_amdgcn_mfma_f32_16x16x32_bf16(__builtin_bit_cast(bf16x8, xa3), __builtin_bit_cast(bf16x8, bfr[19]), a0b, 0, 0, 0);
      a1b = __builtin_amdgcn_mfma_f32_16x16x32_bf16(__builtin_bit_cast(bf16x8, xa3), __builtin_bit_cast(bf16x8, bfr[39]), a1b, 0, 0, 0);
    }

    if (t > 0) {
      // ---- poll own 64B segment until every word carries tag t&3 ---------
      const unsigned int tg = (unsigned int)(t & 3);
      const unsigned int* wp = h_words + (((unsigned int)(t & 1)) << 16) + gbase;
      u32x4 v0, v1, v2, v3;
      while (true) {
        LDH(v0, v1, v2, v3, wp);
        bool ok = ((v0[0] >> 30) == tg) & ((v0[1] >> 30) == tg) &
                  ((v0[2] >> 30) == tg) & ((v0[3] >> 30) == tg) &
                  ((v1[0] >> 30) == tg) & ((v1[1] >> 30) == tg) &
                  ((v1[2] >> 30) == tg) & ((v1[3] >> 30) == tg) &
                  ((v2[0] >> 30) == tg) & ((v2[1] >> 30) == tg) &
                  ((v2[2] >> 30) == tg) & ((v2[3] >> 30) == tg) &
                  ((v3[0] >> 30) == tg) & ((v3[1] >> 30) == tg) &
                  ((v3[2] >> 30) == tg) & ((v3[3] >> 30) == tg);
        if (__all(ok)) break;
      }
      // ---- dequant 32 h values -> A_sh[row][32*(tid&15) ..] ---------------
      unsigned short* dst = &A_sh[tid >> 4][(tid & 15) << 5];
      O8 o;
#define DQW(word, k) { unsigned int ww = (word);                           \
        float fa = (float)(ww & 0x7fffu) * DQ - 1.0f;                      \
        float fb = (float)((ww >> 15) & 0x7fffu) * DQ - 1.0f;              \
        o.w[k] = pk_bf16(fa, fb); }
      DQW(v0[0], 0) DQW(v0[1], 1) DQW(v0[2], 2) DQW(v0[3], 3)
      *(us8*)dst = o.v;
      DQW(v1[0], 0) DQW(v1[1], 1) DQW(v1[2], 2) DQW(v1[3], 3)
      *(us8*)(dst + 8) = o.v;
      DQW(v2[0], 0) DQW(v2[1], 1) DQW(v2[2], 2) DQW(v2[3], 3)
      *(us8*)(dst + 16) = o.v;
      DQW(v3[0], 0) DQW(v3[1], 1) DQW(v3[2], 2) DQW(v3[3], 3)
      *(us8*)(dst + 24) = o.v;
#undef DQW
      BAR_LGKM();                                      // B2

      // ---- h-part GEMM: 16 k-tiles x 2 cols, 4-way acc split --------------
      us8 areg[16];
#pragma unroll
      for (int kt = 0; kt < 16; ++kt)
        areg[kt] = *(const us8*)(arow + (kt << 5));
#pragma unroll
      for (int kt = 0; kt < 16; kt += 2) {
        a0a = __builtin_amdgcn_mfma_f32_16x16x32_bf16(__builtin_bit_cast(bf16x8, areg[kt]), __builtin_bit_cast(bf16x8, bfr[kt]), a0a, 0, 0, 0);
        a1a = __builtin_amdgcn_mfma_f32_16x16x32_bf16(__builtin_bit_cast(bf16x8, areg[kt]), __builtin_bit_cast(bf16x8, bfr[20 + kt]), a1a, 0, 0, 0);
        a0b = __builtin_amdgcn_mfma_f32_16x16x32_bf16(__builtin_bit_cast(bf16x8, areg[kt + 1]), __builtin_bit_cast(bf16x8, bfr[kt + 1]), a0b, 0, 0, 0);
        a1b = __builtin_amdgcn_mfma_f32_16x16x32_bf16(__builtin_bit_cast(bf16x8, areg[kt + 1]), __builtin_bit_cast(bf16x8, bfr[21 + kt]), a1b, 0, 0, 0);
      }
    }

    // ---- combine + scatter gates to LDS ------------------------------------
    {
      f32x4 acc0 = a0a + a0b;
      f32x4 acc1 = a1a + a1b;
      const int crow = (lane >> 4) << 2;
      const int ccol = lane & 15;
#pragma unroll
      for (int q = 0; q < 4; ++q) {
        gates_sh[t & 1][crow + q][(wv << 5) + ccol]      = acc0[q];
        gates_sh[t & 1][crow + q][(wv << 5) + 16 + ccol] = acc1[q];
      }
    }
    BAR_LGKM();                                        // B3

    // ---- gate math for 2 units of one row (bias already in acc) -----------
    float2 vi = *(const float2*)&gates_sh[t & 1][r][uo];
    float2 vf = *(const float2*)&gates_sh[t & 1][r][32 + uo];
    float2 vg = *(const float2*)&gates_sh[t & 1][r][64 + uo];
    float2 vo = *(const float2*)&gates_sh[t & 1][r][96 + uo];
    float it0 = sigm(vi.x), ft0 = sigm(vf.x), ot0 = sigm(vo.x);
    c0 = ft0 * c0 + it0 * tanh_f(vg.x);
    float h0 = ot0 * tanh_f(c0);
    float it1 = sigm(vi.y), ft1 = sigm(vf.y), ot1 = sigm(vo.y);
    c1 = ft1 * c1 + it1 * tanh_f(vg.y);
    float h1 = ot1 * tanh_f(c1);

    // ---- publish h_{t+1}: ONE fire-and-forget tagged sc1 store ------------
    {
      unsigned int q0 = (unsigned int)((h0 + 1.0f) * 16383.5f + 0.5f);
      unsigned int q1 = (unsigned int)((h1 + 1.0f) * 16383.5f + 0.5f);
      unsigned int word = q0 | (q1 << 15) | ((((unsigned int)(t + 1)) & 3u) << 30);
      unsigned int* pp = h_words + (((unsigned int)((t + 1) & 1)) << 16) + pbase;
      __hip_atomic_store(pp, word, __ATOMIC_RELAXED, __HIP_MEMORY_SCOPE_AGENT);
    }

    // ---- off-critical-path output writes ----------------------------------
    const size_t gb = (size_t)(b0 + r);
    float2 hv; hv.x = h0; hv.y = h1;
    *(float2*)&out[(((gb << 9) + t) << 9) + ug] = hv;
    if (t == 511) {
      float2 cv; cv.x = c0; cv.y = c1;
      *(float2*)&out[HT_OFF + (gb << 9) + ug] = hv;
      *(float2*)&out[CT_OFF + (gb << 9) + ug] = cv;
    }
  }

  // ---- block 0: finalize deterministic loss sum ---------------------------
  if (bid == 0) {
    float v = partials[tid] + partials[tid + 256];
#pragma unroll
    for (int off = 32; off; off >>= 1) v += __shfl_down(v, off, 64);
    __shared__ float lw[4];
    if ((tid & 63) == 0) lw[tid >> 6] = v;
    __syncthreads();
    if (tid == 0) out[LOSS_OFF] = lw[0] + lw[1] + lw[2] + lw[3];
  }
}

// ---------------------------------------------------------------------------
extern "C" void kernel_launch(void* const* d_in, const int* in_sizes, int n_in,
                              void* d_out, int out_size, void* d_ws, size_t ws_size,
                              hipStream_t stream) {
  if (ws_size < WS_NEEDED) return;
  const float* x       = (const float*)d_in[0];
  const float* whh     = (const float*)d_in[1];
  const float* wih     = (const float*)d_in[2];
  const float* bias    = (const float*)d_in[3];
  const float* whh_mu  = (const float*)d_in[4];
  const float* whh_rho = (const float*)d_in[5];
  const float* wih_mu  = (const float*)d_in[6];
  const float* wih_rho = (const float*)d_in[7];
  const float* b_mu    = (const float*)d_in[8];
  const float* b_rho   = (const float*)d_in[9];
  char* ws = (char*)d_ws;
  unsigned short* w_frag  = (unsigned short*)(ws + WFRAG_OFF);
  unsigned int*   h_words = (unsigned int*)(ws + HBUF_OFF);
  float*          parts   = (float*)(ws + PART_OFF);
  float*          out     = (float*)d_out;

  prep_w<<<640, 256, 0, stream>>>(whh, wih, w_frag, h_words);
  loss_k<<<512, 256, 0, stream>>>(whh, wih, bias, whh_mu, whh_rho,
                                  wih_mu, wih_rho, b_mu, b_rho, parts);

  void* kargs[6];
  kargs[0] = (void*)&x;
  kargs[1] = (void*)&w_frag;
  kargs[2] = (void*)&bias;
  kargs[3] = (void*)&h_words;
  kargs[4] = (void*)&parts;
  kargs[5] = (void*)&out;
  hipLaunchCooperativeKernel((const void*)lstm_k, dim3(256), dim3(256),
                             kargs, 0, stream);
}